// Round 5
// baseline (82.511 us; speedup 1.0000x reference)
//
#include <hip/hip_runtime.h>

#define BATCHES 4
#define NPTS    8192
#define INF32   3.0e38f

typedef _Float16 f16x8 __attribute__((ext_vector_type(8)));
typedef float    f32x4 __attribute__((ext_vector_type(4)));

// ---------------- prep: pack each point into a 16-slot f16 K-vector -------
// A-vec (x pt):  [xh0,xh1,xh2, xl0,xl1,xl2, xh0,xh1,xh2, qh, ql, 1, 1, 0,0,0]
// B-vec (y pt):  [-2yh0..2, -2yh0..2, -2yl0..2, 1, 1, sh, sl, 0,0,0]
// dot(A,B) = q + s - 2*(xh.yh + xl.yh + xh.yl) ~= |x|^2+|y|^2-2x.y  (err ~3e-5)
__device__ inline void fsplit(float v, _Float16& h, _Float16& l) {
    h = (_Float16)v;
    l = (_Float16)(v - (float)h);
}

__global__ __launch_bounds__(256) void chamfer_prep(
    const float* __restrict__ x, const float* __restrict__ y,
    _Float16* __restrict__ pA, _Float16* __restrict__ pB)
{
    int i = blockIdx.x * 256 + threadIdx.x;     // point id 0..32767
    const float* xp = x + (size_t)i * 3;
    const float* yp = y + (size_t)i * 3;
    float x0 = xp[0], x1 = xp[1], x2 = xp[2];
    float y0 = yp[0], y1 = yp[1], y2 = yp[2];

    _Float16 xh[3], xl[3], yh[3], yl[3];
    fsplit(x0, xh[0], xl[0]); fsplit(x1, xh[1], xl[1]); fsplit(x2, xh[2], xl[2]);
    fsplit(y0, yh[0], yl[0]); fsplit(y1, yh[1], yl[1]); fsplit(y2, yh[2], yl[2]);

    float q = fmaf(x2, x2, fmaf(x1, x1, x0 * x0));
    float s = fmaf(y2, y2, fmaf(y1, y1, y0 * y0));
    _Float16 qh, ql, sh, sl;
    fsplit(q, qh, ql); fsplit(s, sh, sl);

    __align__(16) _Float16 av[16];
    __align__(16) _Float16 bv[16];
    #pragma unroll
    for (int k = 0; k < 3; ++k) {
        av[k]     = xh[k];
        av[3 + k] = xl[k];
        av[6 + k] = xh[k];
        bv[k]     = (_Float16)(-2.0f * (float)yh[k]);
        bv[3 + k] = bv[k];
        bv[6 + k] = (_Float16)(-2.0f * (float)yl[k]);
    }
    av[9] = qh; av[10] = ql; av[11] = (_Float16)1.0f; av[12] = (_Float16)1.0f;
    bv[9] = (_Float16)1.0f; bv[10] = (_Float16)1.0f; bv[11] = sh; bv[12] = sl;
    av[13] = av[14] = av[15] = (_Float16)0.0f;
    bv[13] = bv[14] = bv[15] = (_Float16)0.0f;

    int4* dA = (int4*)(pA + (size_t)i * 16);
    int4* dB = (int4*)(pB + (size_t)i * 16);
    dA[0] = ((int4*)av)[0]; dA[1] = ((int4*)av)[1];
    dB[0] = ((int4*)bv)[0]; dB[1] = ((int4*)bv)[1];
}

// ---------------- main: MFMA tiles + dual min-reduction --------------------
// grid 1024 = batch(4) x strip(64: 128 rows) x mrange(4: 2048 cols)
// wave covers 512 cols (32 m-tiles), 8 row-blocks of 16 -> 256 MFMAs/wave.
// A-frag: lane(row=l&15, k=(l>>4)*8+i); B-frag: lane(col=l&15, same k);
// D: col=l&15, row=(l>>4)*4+reg  [m89-verified].
__global__ __launch_bounds__(256) void chamfer_mfma(
    const _Float16* __restrict__ pA, const _Float16* __restrict__ pB,
    float* __restrict__ rowfinal,   // [4][8192], pre-init +inf, atomicMin
    float* __restrict__ colpart)    // [4][64][8192], unique writes
{
    int bid   = blockIdx.x;
    int b     = bid >> 8;
    int rem   = bid & 255;
    int strip = rem >> 2;
    int mr    = rem & 3;
    int tid   = threadIdx.x;
    int wv    = tid >> 6, lane = tid & 63;
    int li    = lane & 15, kh = lane >> 4;
    bool kOK  = (kh < 2);               // k-slots 16..31 are zero padding

    const _Float16* Ab = pA + (size_t)b * NPTS * 16;
    const _Float16* Bb = pB + (size_t)b * NPTS * 16;
    int n0 = strip * 128;
    int c0 = mr * 2048 + wv * 512;

    f16x8 af[8];
    #pragma unroll
    for (int nb = 0; nb < 8; ++nb) {
        f16x8 v = {0, 0, 0, 0, 0, 0, 0, 0};
        if (kOK) v = *(const f16x8*)(Ab + (size_t)(n0 + nb * 16 + li) * 16 + kh * 8);
        af[nb] = v;
    }

    float rmin[8][4];
    #pragma unroll
    for (int nb = 0; nb < 8; ++nb)
        #pragma unroll
        for (int r = 0; r < 4; ++r) rmin[nb][r] = INF32;

    const f32x4 zero = {0.f, 0.f, 0.f, 0.f};

    auto loadB = [&](int col) -> f16x8 {
        f16x8 v = {0, 0, 0, 0, 0, 0, 0, 0};
        if (kOK) v = *(const f16x8*)(Bb + (size_t)(col + li) * 16 + kh * 8);
        return v;
    };

    f16x8 bf = loadB(c0);
    #pragma unroll 1
    for (int t = 0; t < 32; ++t) {
        f16x8 bc = bf;
        bf = loadB(c0 + (((t + 1) & 31) << 4));   // prefetch next tile's frag
        float cmt = INF32;
        #pragma unroll
        for (int nb = 0; nb < 8; ++nb) {
            f32x4 acc = __builtin_amdgcn_mfma_f32_16x16x32_f16(af[nb], bc, zero, 0, 0, 0);
            rmin[nb][0] = fminf(rmin[nb][0], acc[0]);
            rmin[nb][1] = fminf(rmin[nb][1], acc[1]);
            rmin[nb][2] = fminf(rmin[nb][2], acc[2]);
            rmin[nb][3] = fminf(rmin[nb][3], acc[3]);
            cmt = fminf(cmt, fminf(fminf(acc[0], acc[1]), fminf(acc[2], acc[3])));
        }
        // fold col-min across the 4 row-groups (lane>>4)
        cmt = fminf(cmt, __shfl_xor(cmt, 16, 64));
        cmt = fminf(cmt, __shfl_xor(cmt, 32, 64));
        if (lane < 16)
            colpart[((size_t)(b * 64 + strip) << 13) + (size_t)(c0 + (t << 4) + lane)] = cmt;
    }

    // fold row-mins across the 16 cols (lane&15), then 4-contender atomicMin
    #pragma unroll
    for (int nb = 0; nb < 8; ++nb) {
        #pragma unroll
        for (int r = 0; r < 4; ++r) {
            float v = rmin[nb][r];
            v = fminf(v, __shfl_xor(v, 1, 64));
            v = fminf(v, __shfl_xor(v, 2, 64));
            v = fminf(v, __shfl_xor(v, 4, 64));
            v = fminf(v, __shfl_xor(v, 8, 64));
            if (li == 0)
                atomicMin((int*)&rowfinal[b * NPTS + n0 + nb * 16 + kh * 4 + r],
                          __float_as_int(v));
        }
    }
}

// ---------------- stage2: merge col partials over 64 strips ----------------
__global__ __launch_bounds__(256) void chamfer_colmerge(
    const float* __restrict__ colpart, float* __restrict__ colfinal)
{
    int idx = blockIdx.x * 256 + threadIdx.x;   // 0..32767 = (b, m)
    int b = idx >> 13, m = idx & 8191;
    const float* cp = colpart + ((size_t)(b * 64) << 13) + m;
    float v = INF32;
    #pragma unroll 8
    for (int s = 0; s < 64; ++s) v = fminf(v, cp[(size_t)s << 13]);
    colfinal[idx] = v;
}

// ---------------- final reduction (fixed-tree, deterministic) --------------
__global__ __launch_bounds__(256) void chamfer_reduce1(
    const float* __restrict__ minbuf, double* __restrict__ partials)
{
    int base = blockIdx.x * 1024 + threadIdx.x * 4;
    float4 v = *reinterpret_cast<const float4*>(minbuf + base);
    double s = ((double)v.x + (double)v.y) + ((double)v.z + (double)v.w);
    #pragma unroll
    for (int off = 32; off > 0; off >>= 1) s += __shfl_down(s, off, 64);
    __shared__ double sd[4];
    int wid = threadIdx.x >> 6;
    if ((threadIdx.x & 63) == 0) sd[wid] = s;
    __syncthreads();
    if (threadIdx.x == 0)
        partials[blockIdx.x] = (sd[0] + sd[1]) + (sd[2] + sd[3]);
}

__global__ __launch_bounds__(64) void chamfer_reduce2(
    const double* __restrict__ partials, float* __restrict__ out)
{
    double s = partials[threadIdx.x];
    #pragma unroll
    for (int off = 32; off > 0; off >>= 1) s += __shfl_down(s, off, 64);
    if (threadIdx.x == 0)
        out[0] = (float)(s / (double)(BATCHES * NPTS));
}

extern "C" void kernel_launch(void* const* d_in, const int* in_sizes, int n_in,
                              void* d_out, int out_size, void* d_ws, size_t ws_size,
                              hipStream_t stream)
{
    const float* x = (const float*)d_in[0];
    const float* y = (const float*)d_in[1];
    float* out = (float*)d_out;

    // ws layout (~10.75 MB):
    float*    rowfinal = (float*)d_ws;                         // 32768 f
    float*    colfinal = rowfinal + 32768;                     // 32768 f
    float*    colpart  = colfinal + 32768;                     // 4*64*8192 f = 8 MB
    _Float16* pA = (_Float16*)(colpart + (size_t)4 * 64 * 8192);   // 1 MB
    _Float16* pB = pA + (size_t)BATCHES * NPTS * 16;               // 1 MB
    double*   partials = (double*)(pB + (size_t)BATCHES * NPTS * 16);

    // rowfinal -> +3.39e38 (0x7F7F7F7F); colpart/colfinal fully overwritten
    hipMemsetAsync(rowfinal, 0x7F, 32768 * sizeof(float), stream);

    chamfer_prep<<<BATCHES * NPTS / 256, 256, 0, stream>>>(x, y, pA, pB);
    chamfer_mfma<<<1024, 256, 0, stream>>>(pA, pB, rowfinal, colpart);
    chamfer_colmerge<<<128, 256, 0, stream>>>(colpart, colfinal);
    chamfer_reduce1<<<64, 256, 0, stream>>>(rowfinal, partials);  // rowfinal||colfinal
    chamfer_reduce2<<<1, 64, 0, stream>>>(partials, out);
}

// Round 6
// 45.374 us; speedup vs baseline: 1.8185x; 1.8185x over previous
//
#include <hip/hip_runtime.h>

#define BATCHES 4
#define NPTS    8192
#define INF32   3.0e38f

typedef _Float16 f16x8  __attribute__((ext_vector_type(8)));
typedef float    f32x16 __attribute__((ext_vector_type(16)));

// ---------------- prep: pack each point into a 16-slot f16 K-vector -------
// A-vec (x pt):  [xh0..2, xl0..2, xh0..2, qh, ql, 1, 1, 0,0,0]
// B-vec (y pt):  [-2yh0..2, -2yh0..2, -2yl0..2, 1, 1, sh, sl, 0,0,0]
// dot(A,B) = q + s - 2*(xh.yh + xl.yh + xh.yl)  (exact products; err ~1e-5)
__device__ inline void fsplit(float v, _Float16& h, _Float16& l) {
    h = (_Float16)v;
    l = (_Float16)(v - (float)h);
}

__global__ __launch_bounds__(256) void chamfer_prep(
    const float* __restrict__ x, const float* __restrict__ y,
    _Float16* __restrict__ pA, _Float16* __restrict__ pB)
{
    int i = blockIdx.x * 256 + threadIdx.x;     // point id 0..32767
    const float* xp = x + (size_t)i * 3;
    const float* yp = y + (size_t)i * 3;
    float x0 = xp[0], x1 = xp[1], x2 = xp[2];
    float y0 = yp[0], y1 = yp[1], y2 = yp[2];

    _Float16 xh[3], xl[3], yh[3], yl[3];
    fsplit(x0, xh[0], xl[0]); fsplit(x1, xh[1], xl[1]); fsplit(x2, xh[2], xl[2]);
    fsplit(y0, yh[0], yl[0]); fsplit(y1, yh[1], yl[1]); fsplit(y2, yh[2], yl[2]);

    float q = fmaf(x2, x2, fmaf(x1, x1, x0 * x0));
    float s = fmaf(y2, y2, fmaf(y1, y1, y0 * y0));
    _Float16 qh, ql, sh, sl;
    fsplit(q, qh, ql); fsplit(s, sh, sl);

    __align__(16) _Float16 av[16];
    __align__(16) _Float16 bv[16];
    #pragma unroll
    for (int k = 0; k < 3; ++k) {
        av[k]     = xh[k];
        av[3 + k] = xl[k];
        av[6 + k] = xh[k];
        bv[k]     = (_Float16)(-2.0f * (float)yh[k]);
        bv[3 + k] = bv[k];
        bv[6 + k] = (_Float16)(-2.0f * (float)yl[k]);
    }
    av[9] = qh; av[10] = ql; av[11] = (_Float16)1.0f; av[12] = (_Float16)1.0f;
    bv[9] = (_Float16)1.0f; bv[10] = (_Float16)1.0f; bv[11] = sh; bv[12] = sl;
    av[13] = av[14] = av[15] = (_Float16)0.0f;
    bv[13] = bv[14] = bv[15] = (_Float16)0.0f;

    int4* dA = (int4*)(pA + (size_t)i * 16);
    int4* dB = (int4*)(pB + (size_t)i * 16);
    dA[0] = ((int4*)av)[0]; dA[1] = ((int4*)av)[1];
    dB[0] = ((int4*)bv)[0]; dB[1] = ((int4*)bv)[1];
}

// ---------------- main: 32x32x16 MFMA tiles + dual min-reduction -----------
// grid 2048 = batch(4) x strip(64: 128 rows) x crange(8: 1024 cols)
// wave owns 32 rows, iterates 32 col-tiles of 32. 32 MFMAs/wave.
// A-frag: lane(row=l&31, k=(l>>5)*8+i); B-frag: lane(col=l&31, same k).
// D: col=l&31, row=(reg&3)+8*(reg>>2)+4*(l>>5)  [m74/m101].
__global__ __launch_bounds__(256) void chamfer_mfma(
    const _Float16* __restrict__ pA, const _Float16* __restrict__ pB,
    float* __restrict__ rowfinal,   // [4][8192], pre-init +inf bits, atomicMin
    float* __restrict__ colfinal)   // [4][8192], pre-init +inf bits, atomicMin
{
    int bid   = blockIdx.x;
    int b     = bid >> 9;          // 512 blocks per batch
    int rem   = bid & 511;
    int strip = rem >> 3;          // 0..63 -> 128 rows
    int cr    = rem & 7;           // 0..7  -> 1024 cols
    int tid   = threadIdx.x;
    int wv    = tid >> 6, lane = tid & 63;
    int lo    = lane & 31, hi = lane >> 5;

    const _Float16* Ab = pA + (size_t)b * NPTS * 16;
    const _Float16* Bb = pB + (size_t)b * NPTS * 16;
    int rw = strip * 128 + wv * 32;    // wave's row base
    int c0 = cr * 1024;                // block's col base

    __shared__ int colmin[1024];
    for (int i = tid; i < 1024; i += 256) colmin[i] = 0x7F7F7F7F;
    __syncthreads();

    f16x8 af = *(const f16x8*)(Ab + (size_t)(rw + lo) * 16 + hi * 8);

    float rmin[16];
    #pragma unroll
    for (int r = 0; r < 16; ++r) rmin[r] = INF32;

    const f32x16 zero = {0.f,0.f,0.f,0.f,0.f,0.f,0.f,0.f,
                         0.f,0.f,0.f,0.f,0.f,0.f,0.f,0.f};

    auto loadB = [&](int t) -> f16x8 {
        return *(const f16x8*)(Bb + (size_t)(c0 + ((t & 31) << 5) + lo) * 16 + hi * 8);
    };

#define CHAMFER_BODY(P, Q, TT)                                                  \
    {                                                                           \
        f32x16 A = __builtin_amdgcn_mfma_f32_32x32x16_f16(af, P, zero, 0, 0, 0);\
        f32x16 B = __builtin_amdgcn_mfma_f32_32x32x16_f16(af, Q, zero, 0, 0, 0);\
        _Pragma("unroll")                                                       \
        for (int r = 0; r < 16; ++r)                                            \
            rmin[r] = fminf(fminf(A[r], B[r]), rmin[r]);      /* v_min3 */      \
        float ca = fminf(fminf(A[0], A[1]), A[2]);                              \
        ca = fminf(fminf(ca, A[3]), A[4]);                                      \
        ca = fminf(fminf(ca, A[5]), A[6]);                                      \
        ca = fminf(fminf(ca, A[7]), A[8]);                                      \
        ca = fminf(fminf(ca, A[9]), A[10]);                                     \
        ca = fminf(fminf(ca, A[11]), A[12]);                                    \
        ca = fminf(fminf(ca, A[13]), A[14]);                                    \
        ca = fminf(ca, A[15]);                                                  \
        float cb = fminf(fminf(B[0], B[1]), B[2]);                              \
        cb = fminf(fminf(cb, B[3]), B[4]);                                      \
        cb = fminf(fminf(cb, B[5]), B[6]);                                      \
        cb = fminf(fminf(cb, B[7]), B[8]);                                      \
        cb = fminf(fminf(cb, B[9]), B[10]);                                     \
        cb = fminf(fminf(cb, B[11]), B[12]);                                    \
        cb = fminf(fminf(cb, B[13]), B[14]);                                    \
        cb = fminf(cb, B[15]);                                                  \
        ca = fminf(ca, __shfl_xor(ca, 32, 64));                                 \
        cb = fminf(cb, __shfl_xor(cb, 32, 64));                                 \
        if (lane < 32) {                                                        \
            atomicMin(&colmin[((TT) << 5) + lane],                              \
                      __float_as_int(fmaxf(ca, 0.f)));                          \
            atomicMin(&colmin[((TT) + 1 << 5) + lane],                          \
                      __float_as_int(fmaxf(cb, 0.f)));                          \
        }                                                                       \
    }

    f16x8 p0 = loadB(0), p1 = loadB(1);
    #pragma unroll 1
    for (int t = 0; t < 32; t += 4) {
        f16x8 q0 = loadB(t + 2), q1 = loadB(t + 3);
        CHAMFER_BODY(p0, p1, t)
        p0 = loadB(t + 4); p1 = loadB(t + 5);
        CHAMFER_BODY(q0, q1, t + 2)
    }
#undef CHAMFER_BODY

    // fold row-mins across cols (lane bits 0-4), then atomicMin per row
    #pragma unroll
    for (int r = 0; r < 16; ++r) {
        float v = rmin[r];
        v = fminf(v, __shfl_xor(v, 1, 64));
        v = fminf(v, __shfl_xor(v, 2, 64));
        v = fminf(v, __shfl_xor(v, 4, 64));
        v = fminf(v, __shfl_xor(v, 8, 64));
        v = fminf(v, __shfl_xor(v, 16, 64));
        if (lo == 0) {
            int row = rw + (r & 3) + ((r >> 2) << 3) + (hi << 2);
            atomicMin((int*)&rowfinal[b * NPTS + row],
                      __float_as_int(fmaxf(v, 0.f)));
        }
    }

    __syncthreads();
    for (int i = tid; i < 1024; i += 256)
        atomicMin((int*)&colfinal[b * NPTS + c0 + i], colmin[i]);
}

// ---------------- final reduction (fixed-tree, deterministic) --------------
__global__ __launch_bounds__(256) void chamfer_reduce1(
    const float* __restrict__ minbuf, double* __restrict__ partials)
{
    int base = blockIdx.x * 1024 + threadIdx.x * 4;
    float4 v = *reinterpret_cast<const float4*>(minbuf + base);
    double s = ((double)v.x + (double)v.y) + ((double)v.z + (double)v.w);
    #pragma unroll
    for (int off = 32; off > 0; off >>= 1) s += __shfl_down(s, off, 64);
    __shared__ double sd[4];
    int wid = threadIdx.x >> 6;
    if ((threadIdx.x & 63) == 0) sd[wid] = s;
    __syncthreads();
    if (threadIdx.x == 0)
        partials[blockIdx.x] = (sd[0] + sd[1]) + (sd[2] + sd[3]);
}

__global__ __launch_bounds__(64) void chamfer_reduce2(
    const double* __restrict__ partials, float* __restrict__ out)
{
    double s = partials[threadIdx.x];
    #pragma unroll
    for (int off = 32; off > 0; off >>= 1) s += __shfl_down(s, off, 64);
    if (threadIdx.x == 0)
        out[0] = (float)(s / (double)(BATCHES * NPTS));
}

extern "C" void kernel_launch(void* const* d_in, const int* in_sizes, int n_in,
                              void* d_out, int out_size, void* d_ws, size_t ws_size,
                              hipStream_t stream)
{
    const float* x = (const float*)d_in[0];
    const float* y = (const float*)d_in[1];
    float* out = (float*)d_out;

    // ws layout (~2.3 MB):
    float*    rowfinal = (float*)d_ws;                               // 32768 f
    float*    colfinal = rowfinal + 32768;                           // 32768 f
    _Float16* pA = (_Float16*)(colfinal + 32768);                    // 1 MB
    _Float16* pB = pA + (size_t)BATCHES * NPTS * 16;                 // 1 MB
    double*   partials = (double*)(pB + (size_t)BATCHES * NPTS * 16);

    // rowfinal||colfinal -> +3.39e38 bits (0x7F7F7F7F), one 256 KB memset
    hipMemsetAsync(rowfinal, 0x7F, (size_t)65536 * sizeof(float), stream);

    chamfer_prep<<<BATCHES * NPTS / 256, 256, 0, stream>>>(x, y, pA, pB);
    chamfer_mfma<<<2048, 256, 0, stream>>>(pA, pB, rowfinal, colfinal);
    chamfer_reduce1<<<64, 256, 0, stream>>>(rowfinal, partials);  // rowfinal||colfinal
    chamfer_reduce2<<<1, 64, 0, stream>>>(partials, out);
}

// Round 7
// 42.926 us; speedup vs baseline: 1.9222x; 1.0570x over previous
//
#include <hip/hip_runtime.h>

#define BATCHES 4
#define NPTS    8192
#define INF32   3.0e38f

typedef _Float16 f16x8  __attribute__((ext_vector_type(8)));
typedef float    f32x16 __attribute__((ext_vector_type(16)));

// ---------------- prep: pack each point into a 16-slot f16 K-vector -------
// A-vec (x pt):  [xh0..2, xl0..2, xh0..2, qh, ql, 1, 1, 0,0,0]
// B-vec (y pt):  [-2yh0..2, -2yh0..2, -2yl0..2, 1, 1, sh, sl, 0,0,0]
// dot(A,B) = q + s - 2*(xh.yh + xl.yh + xh.yl)  (exact products; err ~1e-5)
// Also initializes rowfinal/colfinal to +3.39e38 bits (replaces the 40us
// rocclr fillBuffer kernel observed in R6).
__device__ inline void fsplit(float v, _Float16& h, _Float16& l) {
    h = (_Float16)v;
    l = (_Float16)(v - (float)h);
}

__global__ __launch_bounds__(256) void chamfer_prep(
    const float* __restrict__ x, const float* __restrict__ y,
    _Float16* __restrict__ pA, _Float16* __restrict__ pB,
    int* __restrict__ mininit /* rowfinal||colfinal, 65536 ints */)
{
    int i = blockIdx.x * 256 + threadIdx.x;     // point id 0..32767
    mininit[i]         = 0x7F7F7F7F;
    mininit[i + 32768] = 0x7F7F7F7F;

    const float* xp = x + (size_t)i * 3;
    const float* yp = y + (size_t)i * 3;
    float x0 = xp[0], x1 = xp[1], x2 = xp[2];
    float y0 = yp[0], y1 = yp[1], y2 = yp[2];

    _Float16 xh[3], xl[3], yh[3], yl[3];
    fsplit(x0, xh[0], xl[0]); fsplit(x1, xh[1], xl[1]); fsplit(x2, xh[2], xl[2]);
    fsplit(y0, yh[0], yl[0]); fsplit(y1, yh[1], yl[1]); fsplit(y2, yh[2], yl[2]);

    float q = fmaf(x2, x2, fmaf(x1, x1, x0 * x0));
    float s = fmaf(y2, y2, fmaf(y1, y1, y0 * y0));
    _Float16 qh, ql, sh, sl;
    fsplit(q, qh, ql); fsplit(s, sh, sl);

    __align__(16) _Float16 av[16];
    __align__(16) _Float16 bv[16];
    #pragma unroll
    for (int k = 0; k < 3; ++k) {
        av[k]     = xh[k];
        av[3 + k] = xl[k];
        av[6 + k] = xh[k];
        bv[k]     = (_Float16)(-2.0f * (float)yh[k]);
        bv[3 + k] = bv[k];
        bv[6 + k] = (_Float16)(-2.0f * (float)yl[k]);
    }
    av[9] = qh; av[10] = ql; av[11] = (_Float16)1.0f; av[12] = (_Float16)1.0f;
    bv[9] = (_Float16)1.0f; bv[10] = (_Float16)1.0f; bv[11] = sh; bv[12] = sl;
    av[13] = av[14] = av[15] = (_Float16)0.0f;
    bv[13] = bv[14] = bv[15] = (_Float16)0.0f;

    int4* dA = (int4*)(pA + (size_t)i * 16);
    int4* dB = (int4*)(pB + (size_t)i * 16);
    dA[0] = ((int4*)av)[0]; dA[1] = ((int4*)av)[1];
    dB[0] = ((int4*)bv)[0]; dB[1] = ((int4*)bv)[1];
}

// ---------------- main: 32x32x16 MFMA tiles + dual min-reduction -----------
// grid 2048 = batch(4) x strip(64: 128 rows) x crange(8: 1024 cols)
// wave owns 32 rows, iterates 32 col-tiles of 32. 32 MFMAs/wave.
// A-frag: lane(row=l&31, k=(l>>5)*8+i); B-frag: lane(col=l&31, same k).
// D: col=l&31, row=(reg&3)+8*(reg>>2)+4*(l>>5)  [m74/m101].
__global__ __launch_bounds__(256) void chamfer_mfma(
    const _Float16* __restrict__ pA, const _Float16* __restrict__ pB,
    float* __restrict__ rowfinal,   // [4][8192], pre-init +inf bits, atomicMin
    float* __restrict__ colfinal)   // [4][8192], pre-init +inf bits, atomicMin
{
    int bid   = blockIdx.x;
    int b     = bid >> 9;          // 512 blocks per batch
    int rem   = bid & 511;
    int strip = rem >> 3;          // 0..63 -> 128 rows
    int cr    = rem & 7;           // 0..7  -> 1024 cols
    int tid   = threadIdx.x;
    int wv    = tid >> 6, lane = tid & 63;
    int lo    = lane & 31, hi = lane >> 5;

    const _Float16* Ab = pA + (size_t)b * NPTS * 16;
    const _Float16* Bb = pB + (size_t)b * NPTS * 16;
    int rw = strip * 128 + wv * 32;    // wave's row base
    int c0 = cr * 1024;                // block's col base

    __shared__ int colmin[1024];
    for (int i = tid; i < 1024; i += 256) colmin[i] = 0x7F7F7F7F;
    __syncthreads();

    f16x8 af = *(const f16x8*)(Ab + (size_t)(rw + lo) * 16 + hi * 8);

    float rmin[16];
    #pragma unroll
    for (int r = 0; r < 16; ++r) rmin[r] = INF32;

    const f32x16 zero = {0.f,0.f,0.f,0.f,0.f,0.f,0.f,0.f,
                         0.f,0.f,0.f,0.f,0.f,0.f,0.f,0.f};

    auto loadB = [&](int t) -> f16x8 {
        return *(const f16x8*)(Bb + (size_t)(c0 + ((t & 31) << 5) + lo) * 16 + hi * 8);
    };

#define CHAMFER_BODY(P, Q, TT)                                                  \
    {                                                                           \
        f32x16 A = __builtin_amdgcn_mfma_f32_32x32x16_f16(af, P, zero, 0, 0, 0);\
        f32x16 B = __builtin_amdgcn_mfma_f32_32x32x16_f16(af, Q, zero, 0, 0, 0);\
        _Pragma("unroll")                                                       \
        for (int r = 0; r < 16; ++r)                                            \
            rmin[r] = fminf(fminf(A[r], B[r]), rmin[r]);      /* v_min3 */      \
        float ca = fminf(fminf(A[0], A[1]), A[2]);                              \
        ca = fminf(fminf(ca, A[3]), A[4]);                                      \
        ca = fminf(fminf(ca, A[5]), A[6]);                                      \
        ca = fminf(fminf(ca, A[7]), A[8]);                                      \
        ca = fminf(fminf(ca, A[9]), A[10]);                                     \
        ca = fminf(fminf(ca, A[11]), A[12]);                                    \
        ca = fminf(fminf(ca, A[13]), A[14]);                                    \
        ca = fminf(ca, A[15]);                                                  \
        float cb = fminf(fminf(B[0], B[1]), B[2]);                              \
        cb = fminf(fminf(cb, B[3]), B[4]);                                      \
        cb = fminf(fminf(cb, B[5]), B[6]);                                      \
        cb = fminf(fminf(cb, B[7]), B[8]);                                      \
        cb = fminf(fminf(cb, B[9]), B[10]);                                     \
        cb = fminf(fminf(cb, B[11]), B[12]);                                    \
        cb = fminf(fminf(cb, B[13]), B[14]);                                    \
        cb = fminf(cb, B[15]);                                                  \
        ca = fminf(ca, __shfl_xor(ca, 32, 64));                                 \
        cb = fminf(cb, __shfl_xor(cb, 32, 64));                                 \
        if (lane < 32) {                                                        \
            atomicMin(&colmin[((TT) << 5) + lane],                              \
                      __float_as_int(fmaxf(ca, 0.f)));                          \
            atomicMin(&colmin[(((TT) + 1) << 5) + lane],                        \
                      __float_as_int(fmaxf(cb, 0.f)));                          \
        }                                                                       \
    }

    f16x8 p0 = loadB(0), p1 = loadB(1);
    #pragma unroll 1
    for (int t = 0; t < 32; t += 4) {
        f16x8 q0 = loadB(t + 2), q1 = loadB(t + 3);
        CHAMFER_BODY(p0, p1, t)
        p0 = loadB(t + 4); p1 = loadB(t + 5);
        CHAMFER_BODY(q0, q1, t + 2)
    }
#undef CHAMFER_BODY

    // fold row-mins across cols (lane bits 0-4), then atomicMin per row
    #pragma unroll
    for (int r = 0; r < 16; ++r) {
        float v = rmin[r];
        v = fminf(v, __shfl_xor(v, 1, 64));
        v = fminf(v, __shfl_xor(v, 2, 64));
        v = fminf(v, __shfl_xor(v, 4, 64));
        v = fminf(v, __shfl_xor(v, 8, 64));
        v = fminf(v, __shfl_xor(v, 16, 64));
        if (lo == 0) {
            int row = rw + (r & 3) + ((r >> 2) << 3) + (hi << 2);
            atomicMin((int*)&rowfinal[b * NPTS + row],
                      __float_as_int(fmaxf(v, 0.f)));
        }
    }

    __syncthreads();
    for (int i = tid; i < 1024; i += 256)
        atomicMin((int*)&colfinal[b * NPTS + c0 + i], colmin[i]);
}

// ---------------- final reduction (fixed-tree, deterministic) --------------
__global__ __launch_bounds__(256) void chamfer_reduce1(
    const float* __restrict__ minbuf, double* __restrict__ partials)
{
    int base = blockIdx.x * 1024 + threadIdx.x * 4;
    float4 v = *reinterpret_cast<const float4*>(minbuf + base);
    double s = ((double)v.x + (double)v.y) + ((double)v.z + (double)v.w);
    #pragma unroll
    for (int off = 32; off > 0; off >>= 1) s += __shfl_down(s, off, 64);
    __shared__ double sd[4];
    int wid = threadIdx.x >> 6;
    if ((threadIdx.x & 63) == 0) sd[wid] = s;
    __syncthreads();
    if (threadIdx.x == 0)
        partials[blockIdx.x] = (sd[0] + sd[1]) + (sd[2] + sd[3]);
}

__global__ __launch_bounds__(64) void chamfer_reduce2(
    const double* __restrict__ partials, float* __restrict__ out)
{
    double s = partials[threadIdx.x];
    #pragma unroll
    for (int off = 32; off > 0; off >>= 1) s += __shfl_down(s, off, 64);
    if (threadIdx.x == 0)
        out[0] = (float)(s / (double)(BATCHES * NPTS));
}

extern "C" void kernel_launch(void* const* d_in, const int* in_sizes, int n_in,
                              void* d_out, int out_size, void* d_ws, size_t ws_size,
                              hipStream_t stream)
{
    const float* x = (const float*)d_in[0];
    const float* y = (const float*)d_in[1];
    float* out = (float*)d_out;

    // ws layout (~2.3 MB):
    float*    rowfinal = (float*)d_ws;                               // 32768 f
    float*    colfinal = rowfinal + 32768;                           // 32768 f
    _Float16* pA = (_Float16*)(colfinal + 32768);                    // 1 MB
    _Float16* pB = pA + (size_t)BATCHES * NPTS * 16;                 // 1 MB
    double*   partials = (double*)(pB + (size_t)BATCHES * NPTS * 16);

    chamfer_prep<<<BATCHES * NPTS / 256, 256, 0, stream>>>(x, y, pA, pB,
                                                           (int*)rowfinal);
    chamfer_mfma<<<2048, 256, 0, stream>>>(pA, pB, rowfinal, colfinal);
    chamfer_reduce1<<<64, 256, 0, stream>>>(rowfinal, partials);  // rowfinal||colfinal
    chamfer_reduce2<<<1, 64, 0, stream>>>(partials, out);
}

// Round 8
// 36.732 us; speedup vs baseline: 2.2463x; 1.1686x over previous
//
#include <hip/hip_runtime.h>

#define BATCHES 4
#define NPTS    8192
#define INF32   3.0e38f

typedef _Float16 f16x8  __attribute__((ext_vector_type(8)));
typedef float    f32x16 __attribute__((ext_vector_type(16)));

// ---------------- prep: pack each point into a 16-slot f16 K-vector -------
// A-vec (x pt):  [xh0..2, xl0..2, xh0..2, qh, ql, 1, 1, 0,0,0]
// B-vec (y pt):  [-2yh0..2, -2yh0..2, -2yl0..2, 1, 1, sh, sl, 0,0,0]
// dot(A,B) = q + s - 2*(xh.yh + xl.yh + xh.yl)  (exact products; err ~1e-5)
// Also initializes rowfinal/colfinal to +3.39e38 bits.
__device__ inline void fsplit(float v, _Float16& h, _Float16& l) {
    h = (_Float16)v;
    l = (_Float16)(v - (float)h);
}

__global__ __launch_bounds__(256) void chamfer_prep(
    const float* __restrict__ x, const float* __restrict__ y,
    _Float16* __restrict__ pA, _Float16* __restrict__ pB,
    int* __restrict__ mininit /* rowfinal||colfinal, 65536 ints */)
{
    int i = blockIdx.x * 256 + threadIdx.x;     // point id 0..32767
    mininit[i]         = 0x7F7F7F7F;
    mininit[i + 32768] = 0x7F7F7F7F;

    const float* xp = x + (size_t)i * 3;
    const float* yp = y + (size_t)i * 3;
    float x0 = xp[0], x1 = xp[1], x2 = xp[2];
    float y0 = yp[0], y1 = yp[1], y2 = yp[2];

    _Float16 xh[3], xl[3], yh[3], yl[3];
    fsplit(x0, xh[0], xl[0]); fsplit(x1, xh[1], xl[1]); fsplit(x2, xh[2], xl[2]);
    fsplit(y0, yh[0], yl[0]); fsplit(y1, yh[1], yl[1]); fsplit(y2, yh[2], yl[2]);

    float q = fmaf(x2, x2, fmaf(x1, x1, x0 * x0));
    float s = fmaf(y2, y2, fmaf(y1, y1, y0 * y0));
    _Float16 qh, ql, sh, sl;
    fsplit(q, qh, ql); fsplit(s, sh, sl);

    __align__(16) _Float16 av[16];
    __align__(16) _Float16 bv[16];
    #pragma unroll
    for (int k = 0; k < 3; ++k) {
        av[k]     = xh[k];
        av[3 + k] = xl[k];
        av[6 + k] = xh[k];
        bv[k]     = (_Float16)(-2.0f * (float)yh[k]);
        bv[3 + k] = bv[k];
        bv[6 + k] = (_Float16)(-2.0f * (float)yl[k]);
    }
    av[9] = qh; av[10] = ql; av[11] = (_Float16)1.0f; av[12] = (_Float16)1.0f;
    bv[9] = (_Float16)1.0f; bv[10] = (_Float16)1.0f; bv[11] = sh; bv[12] = sl;
    av[13] = av[14] = av[15] = (_Float16)0.0f;
    bv[13] = bv[14] = bv[15] = (_Float16)0.0f;

    int4* dA = (int4*)(pA + (size_t)i * 16);
    int4* dB = (int4*)(pB + (size_t)i * 16);
    dA[0] = ((int4*)av)[0]; dA[1] = ((int4*)av)[1];
    dB[0] = ((int4*)bv)[0]; dB[1] = ((int4*)bv)[1];
}

// ---------------- main: 32x32x16 MFMA tiles + dual min-reduction -----------
// grid 2048 = batch(4) x strip(64: 128 rows) x crange(8: 1024 cols)
// wave owns 32 rows, iterates 32 col-tiles of 32. 32 MFMAs/wave.
// A-frag: lane(row=l&31, k=(l>>5)*8+i); B-frag: lane(col=l&31, same k).
// D: col=l&31, row=(reg&3)+8*(reg>>2)+4*(l>>5)  [m74/m101].
// launch_bounds(256,4): 128-VGPR cap so two f32x16 accs + rmin[16] stay
// in registers (R7's 64-VGPR default spilled them — suspected 4x cost).
__global__ __launch_bounds__(256, 4) void chamfer_mfma(
    const _Float16* __restrict__ pA, const _Float16* __restrict__ pB,
    float* __restrict__ rowfinal,   // [4][8192], pre-init +inf bits, atomicMin
    float* __restrict__ colfinal)   // [4][8192], pre-init +inf bits, atomicMin
{
    int bid   = blockIdx.x;
    int b     = bid >> 9;          // 512 blocks per batch
    int rem   = bid & 511;
    int strip = rem >> 3;          // 0..63 -> 128 rows
    int cr    = rem & 7;           // 0..7  -> 1024 cols
    int tid   = threadIdx.x;
    int wv    = tid >> 6, lane = tid & 63;
    int lo    = lane & 31, hi = lane >> 5;

    const _Float16* Ab = pA + (size_t)b * NPTS * 16;
    const _Float16* Bb = pB + (size_t)b * NPTS * 16;
    int rw = strip * 128 + wv * 32;    // wave's row base
    int c0 = cr * 1024;                // block's col base

    __shared__ int colmin[1024];
    for (int i = tid; i < 1024; i += 256) colmin[i] = 0x7F7F7F7F;
    __syncthreads();

    f16x8 af = *(const f16x8*)(Ab + (size_t)(rw + lo) * 16 + hi * 8);

    float rmin[16];
    #pragma unroll
    for (int r = 0; r < 16; ++r) rmin[r] = INF32;

    const f32x16 zero = {0.f,0.f,0.f,0.f,0.f,0.f,0.f,0.f,
                         0.f,0.f,0.f,0.f,0.f,0.f,0.f,0.f};

    auto loadB = [&](int t) -> f16x8 {
        return *(const f16x8*)(Bb + (size_t)(c0 + ((t & 31) << 5) + lo) * 16 + hi * 8);
    };

    // col-chain: 8 min3-shaped ops over 16 values
#define COLCHAIN(C, V)                                   \
    float C = fminf(fminf(V[0], V[1]), V[2]);            \
    C = fminf(fminf(C, V[3]),  V[4]);                    \
    C = fminf(fminf(C, V[5]),  V[6]);                    \
    C = fminf(fminf(C, V[7]),  V[8]);                    \
    C = fminf(fminf(C, V[9]),  V[10]);                   \
    C = fminf(fminf(C, V[11]), V[12]);                   \
    C = fminf(fminf(C, V[13]), V[14]);                   \
    C = fminf(C, V[15]);

#define CHAMFER_BODY(P, Q, TT)                                                  \
    {                                                                           \
        f32x16 A = __builtin_amdgcn_mfma_f32_32x32x16_f16(af, P, zero, 0, 0, 0);\
        f32x16 B = __builtin_amdgcn_mfma_f32_32x32x16_f16(af, Q, zero, 0, 0, 0);\
        _Pragma("unroll")                                                       \
        for (int r = 0; r < 16; ++r)                                            \
            rmin[r] = fminf(fminf(A[r], B[r]), rmin[r]);      /* v_min3 */      \
        COLCHAIN(ca, A)                                                         \
        COLCHAIN(cb, B)                                                         \
        ca = fminf(ca, __shfl_xor(ca, 32, 64));                                 \
        cb = fminf(cb, __shfl_xor(cb, 32, 64));                                 \
        /* lanes<32 write tile A's cols, lanes>=32 write tile B's cols */       \
        float cw  = (hi == 0) ? ca : cb;                                        \
        int   cix = (((TT) + hi) << 5) + lo;                                    \
        atomicMin(&colmin[cix], __float_as_int(fmaxf(cw, 0.f)));                \
    }

    f16x8 p0 = loadB(0), p1 = loadB(1);
    #pragma unroll 1
    for (int t = 0; t < 32; t += 4) {
        f16x8 q0 = loadB(t + 2), q1 = loadB(t + 3);
        CHAMFER_BODY(p0, p1, t)
        p0 = loadB(t + 4); p1 = loadB(t + 5);
        CHAMFER_BODY(q0, q1, t + 2)
    }
#undef CHAMFER_BODY
#undef COLCHAIN

    // fold row-mins across cols (lane bits 0-4), then atomicMin per row
    #pragma unroll
    for (int r = 0; r < 16; ++r) {
        float v = rmin[r];
        v = fminf(v, __shfl_xor(v, 1, 64));
        v = fminf(v, __shfl_xor(v, 2, 64));
        v = fminf(v, __shfl_xor(v, 4, 64));
        v = fminf(v, __shfl_xor(v, 8, 64));
        v = fminf(v, __shfl_xor(v, 16, 64));
        if (lo == 0) {
            int row = rw + (r & 3) + ((r >> 2) << 3) + (hi << 2);
            atomicMin((int*)&rowfinal[b * NPTS + row],
                      __float_as_int(fmaxf(v, 0.f)));
        }
    }

    __syncthreads();
    for (int i = tid; i < 1024; i += 256)
        atomicMin((int*)&colfinal[b * NPTS + c0 + i], colmin[i]);
}

// ---------------- final reduction (fixed-tree, deterministic) --------------
__global__ __launch_bounds__(256) void chamfer_reduce1(
    const float* __restrict__ minbuf, double* __restrict__ partials)
{
    int base = blockIdx.x * 1024 + threadIdx.x * 4;
    float4 v = *reinterpret_cast<const float4*>(minbuf + base);
    double s = ((double)v.x + (double)v.y) + ((double)v.z + (double)v.w);
    #pragma unroll
    for (int off = 32; off > 0; off >>= 1) s += __shfl_down(s, off, 64);
    __shared__ double sd[4];
    int wid = threadIdx.x >> 6;
    if ((threadIdx.x & 63) == 0) sd[wid] = s;
    __syncthreads();
    if (threadIdx.x == 0)
        partials[blockIdx.x] = (sd[0] + sd[1]) + (sd[2] + sd[3]);
}

__global__ __launch_bounds__(64) void chamfer_reduce2(
    const double* __restrict__ partials, float* __restrict__ out)
{
    double s = partials[threadIdx.x];
    #pragma unroll
    for (int off = 32; off > 0; off >>= 1) s += __shfl_down(s, off, 64);
    if (threadIdx.x == 0)
        out[0] = (float)(s / (double)(BATCHES * NPTS));
}

extern "C" void kernel_launch(void* const* d_in, const int* in_sizes, int n_in,
                              void* d_out, int out_size, void* d_ws, size_t ws_size,
                              hipStream_t stream)
{
    const float* x = (const float*)d_in[0];
    const float* y = (const float*)d_in[1];
    float* out = (float*)d_out;

    // ws layout (~2.3 MB):
    float*    rowfinal = (float*)d_ws;                               // 32768 f
    float*    colfinal = rowfinal + 32768;                           // 32768 f
    _Float16* pA = (_Float16*)(colfinal + 32768);                    // 1 MB
    _Float16* pB = pA + (size_t)BATCHES * NPTS * 16;                 // 1 MB
    double*   partials = (double*)(pB + (size_t)BATCHES * NPTS * 16);

    chamfer_prep<<<BATCHES * NPTS / 256, 256, 0, stream>>>(x, y, pA, pB,
                                                           (int*)rowfinal);
    chamfer_mfma<<<2048, 256, 0, stream>>>(pA, pB, rowfinal, colfinal);
    chamfer_reduce1<<<64, 256, 0, stream>>>(rowfinal, partials);  // rowfinal||colfinal
    chamfer_reduce2<<<1, 64, 0, stream>>>(partials, out);
}